// Round 5
// baseline (468.170 us; speedup 1.0000x reference)
//
#include <hip/hip_runtime.h>

#define BOX 71
#define NF 32
#define CELLS (BOX * BOX * BOX)          // 357,911 cells in batch slice 0
#define SLICE_FLOATS (CELLS * NF)        // 11,453,152 floats = 45.8 MB
#define MAX_DIST_F 35.0f
#define CAP 8                            // bucket capacity per cell (Poisson λ≈1.04)
#define OVF_MAX 65536                    // overflow list capacity (expected ~0 entries)

typedef float vfloat4 __attribute__((ext_vector_type(4)));
typedef int   vint4   __attribute__((ext_vector_type(4)));

// ---- ws layout (bytes, all 16B-aligned) ----
#define COUNTS_PAD_INTS 357912                       // CELLS padded to /4
#define OFF_BUCKETS (COUNTS_PAD_INTS * 4)            // 1,431,648
#define OFF_OVFCNT  (OFF_BUCKETS + CELLS * CAP * 4)  // 12,884,800
#define OFF_OVFLIST (OFF_OVFCNT + 16)                // 12,884,816
#define WS_NEEDED   (OFF_OVFLIST + OVF_MAX * 4)      // ~13.1 MB

__device__ __forceinline__ int cell_of(const float* coords, int p, bool* in_box) {
    // jnp.round = round-half-to-even; rintf matches (RNE default). /1.0 exact.
    int gx = (int)rintf(coords[p * 3 + 0] + MAX_DIST_F);
    int gy = (int)rintf(coords[p * 3 + 1] + MAX_DIST_F);
    int gz = (int)rintf(coords[p * 3 + 2] + MAX_DIST_F);
    *in_box = (gx >= 0) & (gx < BOX) & (gy >= 0) & (gy < BOX) & (gz >= 0) & (gz < BOX);
    return (gx * BOX + gy) * BOX + gz;
}

// Z0: zero the per-cell counts + overflow counter (ws is 0xAA-poisoned each call).
__global__ __launch_bounds__(256) void MakeGrid_zero_ws(
    vint4* __restrict__ counts4, int n4, int* __restrict__ ovfcnt)
{
    int stride = gridDim.x * blockDim.x;
    vint4 z = {0, 0, 0, 0};
    for (int i = blockIdx.x * blockDim.x + threadIdx.x; i < n4; i += stride)
        counts4[i] = z;
    if (blockIdx.x == 0 && threadIdx.x == 0) *ovfcnt = 0;
}

// A: bin points into fixed-capacity buckets. ONE int atomic per point
// (vs 32 fp atomics in the old scatter). Overflow (statistically ~0) -> list.
__global__ __launch_bounds__(256) void MakeGrid_bin(
    const float* __restrict__ coords, int total_points,
    int* __restrict__ counts, int* __restrict__ buckets,
    int* __restrict__ ovfcnt, int* __restrict__ ovflist)
{
    int p = blockIdx.x * blockDim.x + threadIdx.x;
    if (p >= total_points) return;
    bool in_box;
    int cell = cell_of(coords, p, &in_box);
    if (!in_box) return;                 // reference adds 0 at clamped index -> no-op
    int r = atomicAdd(&counts[cell], 1);
    if (r < CAP) {
        buckets[cell * CAP + r] = p;
    } else {
        int o = atomicAdd(ovfcnt, 1);
        if (o < OVF_MAX) ovflist[o] = p;
    }
}

// B (fused): 1/4 of blocks accumulate each cell's bucketed points and STORE the
// final value (replaces slice-0 zeroing; no fp atomics -> pure BW work). The
// other 3/4 stream-zero slices 1..7. Both sides BW-bound -> costs compose
// additively: ~(63+320)MB / 6.2 TB/s ~= 63 us.
__global__ __launch_bounds__(256) void MakeGrid_accum_zero(
    const float* __restrict__ features,
    const int* __restrict__ counts, const int* __restrict__ buckets,
    float* __restrict__ grid,          // slice 0 base
    vfloat4* __restrict__ rest,        // slices 1..7 base
    size_t rest_n4)
{
    int b = blockIdx.x, tid = threadIdx.x;
    if ((b & 3) == 0) {
        // 32-lane group per cell; 8 cells per block-iteration; consecutive
        // blocks -> consecutive cells -> contiguous 1KB stores per block.
        int sb = b >> 2;                               // [0, gridDim/4)
        int group = tid >> 5, f = tid & 31;
        int cstride = (gridDim.x >> 2) * 8;            // cells per sweep
        for (int cell = sb * 8 + group; cell < CELLS; cell += cstride) {
            int c = counts[cell];
            c = c > CAP ? CAP : c;
            float s = 0.f;
            const int* bk = &buckets[(size_t)cell * CAP];
            for (int i = 0; i < c; ++i) {
                int p = bk[i];                          // broadcast across group
                s += features[(size_t)p * NF + f];      // 128B coalesced gather
            }
            __builtin_nontemporal_store(s, &grid[(size_t)cell * NF + f]);
        }
    } else {
        size_t zb = (size_t)(b >> 2) * 3 + (size_t)(b & 3) - 1;
        size_t stride = ((size_t)gridDim.x >> 2) * 3 * blockDim.x;
        vfloat4 z = {0.f, 0.f, 0.f, 0.f};
        for (size_t i = zb * blockDim.x + tid; i < rest_n4; i += stride)
            __builtin_nontemporal_store(z, &rest[i]);
    }
}

// C: exact handling of bucket-overflow points (expected ~0): fp atomics onto
// B's stored sums. Stream order guarantees these land after B's stores.
__global__ __launch_bounds__(256) void MakeGrid_overflow(
    const float* __restrict__ coords, const float* __restrict__ features,
    float* __restrict__ grid,
    const int* __restrict__ ovfcnt, const int* __restrict__ ovflist)
{
    int n = *ovfcnt;
    n = n > OVF_MAX ? OVF_MAX : n;
    int total = n * NF;
    int stride = gridDim.x * blockDim.x;
    for (int t = blockIdx.x * blockDim.x + threadIdx.x; t < total; t += stride) {
        int p = ovflist[t >> 5], f = t & 31;
        bool in_box;
        int cell = cell_of(coords, p, &in_box);        // always in-box by construction
        atomicAdd(&grid[(size_t)cell * NF + f], features[(size_t)p * NF + f]);
    }
}

// ---- fallback path (ws too small): proven R2 structure ----
__global__ __launch_bounds__(256) void MakeGrid_zero_all(
    vfloat4* __restrict__ out, size_t n4)
{
    size_t stride = (size_t)gridDim.x * blockDim.x;
    vfloat4 z = {0.f, 0.f, 0.f, 0.f};
    for (size_t i = (size_t)blockIdx.x * blockDim.x + threadIdx.x; i < n4; i += stride)
        out[i] = z;
}

__global__ __launch_bounds__(256) void MakeGrid_scatter_atomic(
    const float* __restrict__ coords, const float* __restrict__ features,
    float* __restrict__ grid, int total_points)
{
    int t = blockIdx.x * blockDim.x + threadIdx.x;
    int p = t >> 5, f = t & 31;
    if (p >= total_points) return;
    bool in_box;
    int cell = cell_of(coords, p, &in_box);
    if (!in_box) return;
    atomicAdd(&grid[(size_t)cell * NF + f], features[(size_t)p * NF + f]);
}

extern "C" void kernel_launch(void* const* d_in, const int* in_sizes, int n_in,
                              void* d_out, int out_size, void* d_ws, size_t ws_size,
                              hipStream_t stream) {
    const float* coords   = (const float*)d_in[0];  // [B,N,3] fp32
    const float* features = (const float*)d_in[1];  // [B,N,F] fp32
    float* out = (float*)d_out;                     // [B,71,71,71,F] fp32

    int total_points = in_sizes[0] / 3;             // B*N = 131072

    if (ws_size >= (size_t)WS_NEEDED) {
        char* ws = (char*)d_ws;
        int* counts  = (int*)ws;
        int* buckets = (int*)(ws + OFF_BUCKETS);
        int* ovfcnt  = (int*)(ws + OFF_OVFCNT);
        int* ovflist = (int*)(ws + OFF_OVFLIST);

        MakeGrid_zero_ws<<<128, 256, 0, stream>>>(
            (vint4*)counts, COUNTS_PAD_INTS / 4, ovfcnt);

        MakeGrid_bin<<<(total_points + 255) / 256, 256, 0, stream>>>(
            coords, total_points, counts, buckets, ovfcnt, ovflist);

        size_t rest_n4 = ((size_t)out_size - SLICE_FLOATS) / 4;
        MakeGrid_accum_zero<<<8192, 256, 0, stream>>>(
            features, counts, buckets, out,
            (vfloat4*)(out + SLICE_FLOATS), rest_n4);

        MakeGrid_overflow<<<64, 256, 0, stream>>>(
            coords, features, out, ovfcnt, ovflist);
    } else {
        // Fallback: full zero + direct fp32 atomic scatter (R2, passed).
        MakeGrid_zero_all<<<8192, 256, 0, stream>>>((vfloat4*)out, (size_t)out_size / 4);
        int total_threads = total_points * NF;
        MakeGrid_scatter_atomic<<<(total_threads + 255) / 256, 256, 0, stream>>>(
            coords, features, out, total_points);
    }
}

// Round 6
// 406.139 us; speedup vs baseline: 1.1527x; 1.1527x over previous
//
#include <hip/hip_runtime.h>

#define BOX 71
#define NF 32
#define CELLS (BOX * BOX * BOX)          // 357,911 cells in batch slice 0
#define SLICE_FLOATS (CELLS * NF)        // 11,453,152 floats = 45.8 MB
#define MAX_DIST_F 35.0f
#define CAP 8                            // bucket capacity (Poisson λ≈1.04 at center)
#define OVF_MAX 65536

typedef float vfloat4 __attribute__((ext_vector_type(4)));
typedef int   vint4   __attribute__((ext_vector_type(4)));

// ---- ws layout (bytes, all 16B-aligned) ----
#define COUNTS_PAD_INTS 357912                       // CELLS padded to /4
#define OFF_BUCKETS (COUNTS_PAD_INTS * 4)
#define OFF_OVFCNT  (OFF_BUCKETS + CELLS * CAP * 4)
#define OFF_OVFLIST (OFF_OVFCNT + 16)
#define WS_NEEDED   (OFF_OVFLIST + OVF_MAX * 4)      // ~13.1 MB

__device__ __forceinline__ int cell_of(const float* coords, int p, bool* in_box) {
    // jnp.round = round-half-to-even; rintf matches (RNE default). /1.0 exact.
    int gx = (int)rintf(coords[p * 3 + 0] + MAX_DIST_F);
    int gy = (int)rintf(coords[p * 3 + 1] + MAX_DIST_F);
    int gz = (int)rintf(coords[p * 3 + 2] + MAX_DIST_F);
    *in_box = (gx >= 0) & (gx < BOX) & (gy >= 0) & (gy < BOX) & (gz >= 0) & (gz < BOX);
    return (gx * BOX + gy) * BOX + gz;
}

// K1: zero per-cell counts + overflow counter (ws is 0xAA-poisoned each call).
__global__ __launch_bounds__(256) void MakeGrid_zero_ws(
    vint4* __restrict__ counts4, int n4, int* __restrict__ ovfcnt)
{
    int stride = gridDim.x * blockDim.x;
    vint4 z = {0, 0, 0, 0};
    for (int i = blockIdx.x * blockDim.x + threadIdx.x; i < n4; i += stride)
        counts4[i] = z;
    if (blockIdx.x == 0 && threadIdx.x == 0) *ovfcnt = 0;
}

// K2 (fused): first nb_bin blocks bin points into buckets (one point/thread,
// one int atomic each — tiny, hides under the zero); remaining blocks
// stream-zero slices 1..7 (320.7 MB, BW-bound ~58 us). Disjoint outputs
// (ws vs out) -> no ordering needed between the two halves.
__global__ __launch_bounds__(256) void MakeGrid_bin_zero(
    const float* __restrict__ coords, int total_points,
    int* __restrict__ counts, int* __restrict__ buckets,
    int* __restrict__ ovfcnt, int* __restrict__ ovflist,
    vfloat4* __restrict__ rest, size_t rest_n4, int nb_bin)
{
    int b = blockIdx.x;
    if (b < nb_bin) {
        int p = b * blockDim.x + threadIdx.x;
        if (p >= total_points) return;
        bool in_box;
        int cell = cell_of(coords, p, &in_box);
        if (!in_box) return;             // reference adds 0 at clamped index -> no-op
        int r = atomicAdd(&counts[cell], 1);
        if (r < CAP) {
            buckets[cell * CAP + r] = p;
        } else {
            int o = atomicAdd(ovfcnt, 1);
            if (o < OVF_MAX) ovflist[o] = p;
        }
    } else {
        size_t zb = (size_t)(b - nb_bin);
        size_t stride = (size_t)(gridDim.x - nb_bin) * blockDim.x;
        vfloat4 z = {0.f, 0.f, 0.f, 0.f};
        for (size_t i = zb * blockDim.x + threadIdx.x; i < rest_n4; i += stride)
            __builtin_nontemporal_store(z, &rest[i]);
    }
}

// K3: full-grid accumulate. 8192 blocks x 8 groups = 65536 groups -> 5.5
// cells/group (R5 had 22 -> latency-bound). Flattened chain: count load and
// lane-parallel bucket-row load issue CONCURRENTLY; __shfl broadcasts point
// ids; all <=CAP feature gathers are independent. Chain depth 2 loads.
__global__ __launch_bounds__(256) void MakeGrid_accum(
    const float* __restrict__ features,
    const int* __restrict__ counts, const int* __restrict__ buckets,
    float* __restrict__ grid)
{
    int group = threadIdx.x >> 5, f = threadIdx.x & 31;
    int gstride = gridDim.x * 8;
    for (int cell = blockIdx.x * 8 + group; cell < CELLS; cell += gstride) {
        int c = counts[cell];                        // issues in parallel with:
        int pi = (f < CAP) ? buckets[(size_t)cell * CAP + f] : 0;  // 32B/group row load
        c = c > CAP ? CAP : c;
        float s = 0.f;
        #pragma unroll
        for (int i = 0; i < CAP; ++i) {
            if (i >= c) break;
            int p = __shfl(pi, i, 32);               // bucket slot i (written while all lanes active)
            s += features[(size_t)p * NF + f];       // independent 128B coalesced gathers
        }
        // Group writes 32 consecutive floats; 8 groups/block -> 1KB contiguous.
        __builtin_nontemporal_store(s, &grid[(size_t)cell * NF + f]);
    }
}

// K4: exact handling of bucket-overflow points (expected ~0) via fp atomics
// onto K3's stored sums (stream order guarantees they land after K3).
__global__ __launch_bounds__(256) void MakeGrid_overflow(
    const float* __restrict__ coords, const float* __restrict__ features,
    float* __restrict__ grid,
    const int* __restrict__ ovfcnt, const int* __restrict__ ovflist)
{
    int n = *ovfcnt;
    n = n > OVF_MAX ? OVF_MAX : n;
    int total = n * NF;
    int stride = gridDim.x * blockDim.x;
    for (int t = blockIdx.x * blockDim.x + threadIdx.x; t < total; t += stride) {
        int p = ovflist[t >> 5], f = t & 31;
        bool in_box;
        int cell = cell_of(coords, p, &in_box);      // in-box by construction
        atomicAdd(&grid[(size_t)cell * NF + f], features[(size_t)p * NF + f]);
    }
}

// ---- fallback path (ws too small): proven R2 structure ----
__global__ __launch_bounds__(256) void MakeGrid_zero_all(
    vfloat4* __restrict__ out, size_t n4)
{
    size_t stride = (size_t)gridDim.x * blockDim.x;
    vfloat4 z = {0.f, 0.f, 0.f, 0.f};
    for (size_t i = (size_t)blockIdx.x * blockDim.x + threadIdx.x; i < n4; i += stride)
        out[i] = z;
}

__global__ __launch_bounds__(256) void MakeGrid_scatter_atomic(
    const float* __restrict__ coords, const float* __restrict__ features,
    float* __restrict__ grid, int total_points)
{
    int t = blockIdx.x * blockDim.x + threadIdx.x;
    int p = t >> 5, f = t & 31;
    if (p >= total_points) return;
    bool in_box;
    int cell = cell_of(coords, p, &in_box);
    if (!in_box) return;
    atomicAdd(&grid[(size_t)cell * NF + f], features[(size_t)p * NF + f]);
}

extern "C" void kernel_launch(void* const* d_in, const int* in_sizes, int n_in,
                              void* d_out, int out_size, void* d_ws, size_t ws_size,
                              hipStream_t stream) {
    const float* coords   = (const float*)d_in[0];  // [B,N,3] fp32
    const float* features = (const float*)d_in[1];  // [B,N,F] fp32
    float* out = (float*)d_out;                     // [B,71,71,71,F] fp32

    int total_points = in_sizes[0] / 3;             // B*N = 131072

    if (ws_size >= (size_t)WS_NEEDED) {
        char* ws = (char*)d_ws;
        int* counts  = (int*)ws;
        int* buckets = (int*)(ws + OFF_BUCKETS);
        int* ovfcnt  = (int*)(ws + OFF_OVFCNT);
        int* ovflist = (int*)(ws + OFF_OVFLIST);

        MakeGrid_zero_ws<<<512, 256, 0, stream>>>(
            (vint4*)counts, COUNTS_PAD_INTS / 4, ovfcnt);

        // 512 bin blocks (one point/thread, exactly covers 131072) + 7680 zero blocks.
        int nb_bin = (total_points + 255) / 256;
        size_t rest_n4 = ((size_t)out_size - SLICE_FLOATS) / 4;
        MakeGrid_bin_zero<<<nb_bin + 7680, 256, 0, stream>>>(
            coords, total_points, counts, buckets, ovfcnt, ovflist,
            (vfloat4*)(out + SLICE_FLOATS), rest_n4, nb_bin);

        MakeGrid_accum<<<8192, 256, 0, stream>>>(features, counts, buckets, out);

        MakeGrid_overflow<<<64, 256, 0, stream>>>(
            coords, features, out, ovfcnt, ovflist);
    } else {
        // Fallback: full zero + direct fp32 atomic scatter (R2, passed).
        MakeGrid_zero_all<<<8192, 256, 0, stream>>>((vfloat4*)out, (size_t)out_size / 4);
        int total_threads = total_points * NF;
        MakeGrid_scatter_atomic<<<(total_threads + 255) / 256, 256, 0, stream>>>(
            coords, features, out, total_points);
    }
}